// Round 5
// baseline (341.326 us; speedup 1.0000x reference)
//
#include <hip/hip_runtime.h>
#include <hip/hip_bf16.h>
#include <cstdint>
#include <cstddef>

// Problem constants
#define B_  8192
#define D_  256
#define H_  512
#define K_  1280   // D + 2H
#define N_  2560   // 5H
#define NT_ 160    // N-tile: 2 h-groups of (16 h x 5 gates)

typedef short short8 __attribute__((ext_vector_type(8)));
typedef float f32x4  __attribute__((ext_vector_type(4)));

__device__ __forceinline__ float sigf(float x)     { return 1.f / (1.f + __expf(-x)); }
__device__ __forceinline__ float tanhfast(float x) { return 1.f - 2.f / (__expf(2.f * x) + 1.f); }

// ---------------------------------------------------------------------------
// convA: pack [x | h_t | h_s] -> bf16 A[B_, K_], 8 elems/thread.
// ---------------------------------------------------------------------------
__global__ void convA_kernel(const float* __restrict__ x, const float* __restrict__ ht,
                             const float* __restrict__ hs, __hip_bfloat16* __restrict__ A) {
    int t = blockIdx.x * 256 + threadIdx.x;   // over B_*K_/8 (exact multiple)
    int idx8 = t * 8;
    int b = idx8 / K_;
    int k = idx8 - b * K_;
    const float* src;
    if (k < D_)            src = x  + (size_t)b * D_ + k;
    else if (k < D_ + H_)  src = ht + (size_t)b * H_ + (k - D_);
    else                   src = hs + (size_t)b * H_ + (k - D_ - H_);
    f32x4 v0 = *(const f32x4*)(src);
    f32x4 v1 = *(const f32x4*)(src + 4);
    union { short8 s; __hip_bfloat16 h[8]; } o;
    o.h[0] = __float2bfloat16(v0[0]); o.h[1] = __float2bfloat16(v0[1]);
    o.h[2] = __float2bfloat16(v0[2]); o.h[3] = __float2bfloat16(v0[3]);
    o.h[4] = __float2bfloat16(v1[0]); o.h[5] = __float2bfloat16(v1[1]);
    o.h[6] = __float2bfloat16(v1[2]); o.h[7] = __float2bfloat16(v1[3]);
    *(short8*)(A + idx8) = o.s;
}

// ---------------------------------------------------------------------------
// convW: build bf16 WT[n', k], n' = (h/16)*80 + g*16 + (h%16)  (gate-interleaved)
// ---------------------------------------------------------------------------
struct WPtrs {
    const float* U[5];
    const float* Wt[5];
    const float* Ws[5];
};

__global__ void convW_kernel(WPtrs p, __hip_bfloat16* __restrict__ WT) {
    __shared__ __hip_bfloat16 tile[64][72];  // padded
    int g  = blockIdx.z;
    int k0 = blockIdx.y * 64;
    int h0 = blockIdx.x * 64;
    const float* src; int kl0;
    if (k0 < 256)      { src = p.U[g];  kl0 = k0; }
    else if (k0 < 768) { src = p.Wt[g]; kl0 = k0 - 256; }
    else               { src = p.Ws[g]; kl0 = k0 - 768; }
    int tid = threadIdx.x;
    int tk = tid >> 6;    // 0..3
    int th = tid & 63;
    for (int r = 0; r < 16; ++r) {
        int kl = r * 4 + tk;
        tile[kl][th] = __float2bfloat16(src[(size_t)(kl0 + kl) * H_ + h0 + th]);
    }
    __syncthreads();
    for (int r = 0; r < 16; ++r) {
        int hl = r * 4 + tk;           // h within tile
        int h  = h0 + hl;
        int np = (h >> 4) * 80 + g * 16 + (h & 15);
        WT[(size_t)np * K_ + k0 + th] = tile[th][hl];
    }
}

// ---------------------------------------------------------------------------
// Fused GEMM + LSTM epilogue — BARRIER-FREE direct-load version.
// Each wave loads its MFMA A/B fragments straight from global (L2/L1-hot)
// into VGPRs, register-double-buffered one K-step ahead. No LDS, no
// __syncthreads in the K-loop -> no vmcnt(0) barrier drains; waves pipeline
// independently (AITER-style fine-grained vmcnt from the compiler).
// Fragment addresses reproduce exactly what the LDS roundtrip produced:
//   a[f] lane value = A[(m0+wm*64+f*16+l15)*K_ + kk + quad*8 .. +8]
//   b[j] lane value = WT[(n0+wn*80+j*16+l15)*K_ + kk + quad*8 .. +8]
// ---------------------------------------------------------------------------
__global__ __launch_bounds__(256, 3) void gemm_fused_kernel(
    const __hip_bfloat16* __restrict__ A, const __hip_bfloat16* __restrict__ WT,
    const float* __restrict__ ct, const float* __restrict__ cs,
    const float* __restrict__ bi, const float* __restrict__ bfs,
    const float* __restrict__ bft, const float* __restrict__ bo,
    const float* __restrict__ bc, float* __restrict__ out) {
    int tid = threadIdx.x;
    int m0 = blockIdx.x * 128;   // row tile (fast axis -> XCD = x%8, W col-tile L2-hot)
    int n0 = blockIdx.y * NT_;   // W column tile (slow axis)
    int wid  = tid >> 6, lane = tid & 63;
    int wm   = wid >> 1, wn   = wid & 1;
    int quad = lane >> 4, l15 = lane & 15;

    int h = (blockIdx.y * 2 + wn) * 16 + l15;   // this lane's h column
    float Bi = bi[h], Bfs = bfs[h], Bft = bft[h], Bo = bo[h], Bc = bc[h];

    f32x4 acc[4][5];
#pragma unroll
    for (int i = 0; i < 4; ++i)
#pragma unroll
        for (int j = 0; j < 5; ++j)
            acc[i][j] = (f32x4){0.f, 0.f, 0.f, 0.f};

    const __hip_bfloat16* aRow = A  + (size_t)(m0 + wm * 64 + l15) * K_ + quad * 8;
    const __hip_bfloat16* bRow = WT + (size_t)(n0 + wn * 80 + l15) * K_ + quad * 8;

    short8 ca[4], cb[5], na[4], nb[5];
#pragma unroll
    for (int f = 0; f < 4; ++f) ca[f] = *(const short8*)(aRow + (size_t)f * 16 * K_);
#pragma unroll
    for (int j = 0; j < 5; ++j) cb[j] = *(const short8*)(bRow + (size_t)j * 16 * K_);

    for (int kk = 32; kk < K_; kk += 32) {
        // prefetch next K-step while current MFMAs run
#pragma unroll
        for (int f = 0; f < 4; ++f) na[f] = *(const short8*)(aRow + (size_t)f * 16 * K_ + kk);
#pragma unroll
        for (int j = 0; j < 5; ++j) nb[j] = *(const short8*)(bRow + (size_t)j * 16 * K_ + kk);
#pragma unroll
        for (int j = 0; j < 5; ++j)
#pragma unroll
            for (int i = 0; i < 4; ++i)
                acc[i][j] = __builtin_amdgcn_mfma_f32_16x16x32_bf16(ca[i], cb[j], acc[i][j], 0, 0, 0);
#pragma unroll
        for (int f = 0; f < 4; ++f) ca[f] = na[f];
#pragma unroll
        for (int j = 0; j < 5; ++j) cb[j] = nb[j];
    }
#pragma unroll
    for (int j = 0; j < 5; ++j)
#pragma unroll
        for (int i = 0; i < 4; ++i)
            acc[i][j] = __builtin_amdgcn_mfma_f32_16x16x32_bf16(ca[i], cb[j], acc[i][j], 0, 0, 0);

    // Lane-local LSTM epilogue. C/D layout: col = l15 (h), row = quad*4 + r.
#pragma unroll
    for (int i = 0; i < 4; ++i) {
        int row0 = m0 + wm * 64 + i * 16 + quad * 4;
#pragma unroll
        for (int r = 0; r < 4; ++r) {
            size_t idx = (size_t)(row0 + r) * H_ + h;
            float i_n  = sigf(acc[i][0][r] + Bi);
            float fs_n = sigf(acc[i][1][r] + Bfs);
            float ft_n = sigf(acc[i][2][r] + Bft);
            float o_n  = sigf(acc[i][3][r] + Bo);
            float c_n  = tanhfast(acc[i][4][r] + Bc);
            float ch   = i_n * c_n + ft_n * ct[idx] + fs_n * cs[idx];
            out[idx] = o_n * tanhfast(ch);
            out[(size_t)B_ * H_ + idx] = ch;
        }
    }
}

// ---------------------------------------------------------------------------
// Fallback (ws too small): one block per row, fp32 direct. Slow but correct.
// ---------------------------------------------------------------------------
struct AllW {
    const float* U[5];
    const float* Wt[5];
    const float* Ws[5];
    const float* bias[5];
};

__global__ __launch_bounds__(512) void fallback_kernel(const float* __restrict__ x,
                                                       const float* __restrict__ ht,
                                                       const float* __restrict__ hs,
                                                       const float* __restrict__ ct,
                                                       const float* __restrict__ cs,
                                                       AllW w, float* __restrict__ out) {
    __shared__ float arow[K_];
    int b = blockIdx.x;
    int h = threadIdx.x;
    for (int k = h; k < K_; k += 512) {
        float v;
        if (k < D_)           v = x[b * D_ + k];
        else if (k < D_ + H_) v = ht[b * H_ + k - D_];
        else                  v = hs[b * H_ + k - D_ - H_];
        arow[k] = v;
    }
    __syncthreads();
    float g[5];
    for (int gi = 0; gi < 5; ++gi) {
        float s = w.bias[gi][h];
        const float* U = w.U[gi];
        for (int k = 0; k < D_; ++k) s += arow[k] * U[(size_t)k * H_ + h];
        const float* Wt = w.Wt[gi];
        for (int k = 0; k < H_; ++k) s += arow[D_ + k] * Wt[(size_t)k * H_ + h];
        const float* Ws = w.Ws[gi];
        for (int k = 0; k < H_; ++k) s += arow[D_ + H_ + k] * Ws[(size_t)k * H_ + h];
        g[gi] = s;
    }
    int idx = b * H_ + h;
    float i_n = sigf(g[0]), fs_n = sigf(g[1]), ft_n = sigf(g[2]), o_n = sigf(g[3]);
    float c_n = tanhfast(g[4]);
    float ch  = i_n * c_n + ft_n * ct[idx] + fs_n * cs[idx];
    out[idx] = o_n * tanhfast(ch);
    out[(size_t)B_ * H_ + idx] = ch;
}

// ---------------------------------------------------------------------------
extern "C" void kernel_launch(void* const* d_in, const int* in_sizes, int n_in,
                              void* d_out, int out_size, void* d_ws, size_t ws_size,
                              hipStream_t stream) {
    const float* x  = (const float*)d_in[0];
    const float* ht = (const float*)d_in[1];
    const float* hs = (const float*)d_in[2];
    const float* ct = (const float*)d_in[3];
    const float* cs = (const float*)d_in[4];

    WPtrs wp;
    AllW  aw;
    const float* bias[5];
    for (int g = 0; g < 5; ++g) {
        wp.U[g]  = (const float*)d_in[5 + g * 4 + 0];
        wp.Wt[g] = (const float*)d_in[5 + g * 4 + 1];
        wp.Ws[g] = (const float*)d_in[5 + g * 4 + 2];
        bias[g]  = (const float*)d_in[5 + g * 4 + 3];
        aw.U[g] = wp.U[g]; aw.Wt[g] = wp.Wt[g]; aw.Ws[g] = wp.Ws[g]; aw.bias[g] = bias[g];
    }
    float* out = (float*)d_out;

    size_t szA = (size_t)B_ * K_ * 2;  // 20 MB
    size_t szW = (size_t)N_ * K_ * 2;  // 6.25 MB

    if (ws_size >= szA + szW) {
        __hip_bfloat16* Abf = (__hip_bfloat16*)d_ws;
        __hip_bfloat16* WT  = (__hip_bfloat16*)((char*)d_ws + szA);

        convA_kernel<<<(B_ * K_ / 8) / 256, 256, 0, stream>>>(x, ht, hs, Abf);
        convW_kernel<<<dim3(8, 20, 5), 256, 0, stream>>>(wp, WT);
        gemm_fused_kernel<<<dim3(B_ / 128, N_ / NT_), 256, 0, stream>>>(
            Abf, WT, ct, cs, bias[0], bias[1], bias[2], bias[3], bias[4], out);
    } else {
        fallback_kernel<<<B_, 512, 0, stream>>>(x, ht, hs, ct, cs, aw, out);
    }
}

// Round 6
// 242.567 us; speedup vs baseline: 1.4071x; 1.4071x over previous
//
#include <hip/hip_runtime.h>
#include <hip/hip_bf16.h>
#include <cstdint>
#include <cstddef>

// Problem constants
#define B_  8192
#define D_  256
#define H_  512
#define K_  1280   // D + 2H
#define N_  2560   // 5H
#define NT_ 160    // N-tile: 2 h-groups of (16 h x 5 gates)

typedef short short8 __attribute__((ext_vector_type(8)));
typedef float f32x4  __attribute__((ext_vector_type(4)));

__device__ __forceinline__ float sigf(float x)     { return 1.f / (1.f + __expf(-x)); }
__device__ __forceinline__ float tanhfast(float x) { return 1.f - 2.f / (__expf(2.f * x) + 1.f); }

// ---------------------------------------------------------------------------
// prep: merged convA + convW (one launch).
// Blocks [0, 5120): convA — pack [x | h_t | h_s] -> bf16 A[B_, K_], 8 elem/thr.
// Blocks [5120, 5920): convW — bf16 WT[n',k], n' = (h/16)*80 + g*16 + (h%16).
// ---------------------------------------------------------------------------
struct WPtrs {
    const float* U[5];
    const float* Wt[5];
    const float* Ws[5];
};

__global__ void prep_kernel(const float* __restrict__ x, const float* __restrict__ ht,
                            const float* __restrict__ hs, WPtrs p,
                            __hip_bfloat16* __restrict__ A, __hip_bfloat16* __restrict__ WT) {
    __shared__ __hip_bfloat16 tile[64][72];  // used by convW part only
    int bid = blockIdx.x;
    if (bid < 5120) {
        // ---- convA ----
        int t = bid * 256 + threadIdx.x;   // over B_*K_/8
        int idx8 = t * 8;
        int b = idx8 / K_;
        int k = idx8 - b * K_;
        const float* src;
        if (k < D_)            src = x  + (size_t)b * D_ + k;
        else if (k < D_ + H_)  src = ht + (size_t)b * H_ + (k - D_);
        else                   src = hs + (size_t)b * H_ + (k - D_ - H_);
        f32x4 v0 = *(const f32x4*)(src);
        f32x4 v1 = *(const f32x4*)(src + 4);
        union { short8 s; __hip_bfloat16 h[8]; } o;
        o.h[0] = __float2bfloat16(v0[0]); o.h[1] = __float2bfloat16(v0[1]);
        o.h[2] = __float2bfloat16(v0[2]); o.h[3] = __float2bfloat16(v0[3]);
        o.h[4] = __float2bfloat16(v1[0]); o.h[5] = __float2bfloat16(v1[1]);
        o.h[6] = __float2bfloat16(v1[2]); o.h[7] = __float2bfloat16(v1[3]);
        *(short8*)(A + idx8) = o.s;
    } else {
        // ---- convW ----  bid2 = hblk + 8*(kblk + 20*g)
        int bid2 = bid - 5120;
        int hblk = bid2 & 7;
        int kblk = (bid2 >> 3) % 20;
        int g    = bid2 / 160;
        int k0 = kblk * 64;
        int h0 = hblk * 64;
        const float* src; int kl0;
        if (k0 < 256)      { src = p.U[g];  kl0 = k0; }
        else if (k0 < 768) { src = p.Wt[g]; kl0 = k0 - 256; }
        else               { src = p.Ws[g]; kl0 = k0 - 768; }
        int tid = threadIdx.x;
        int tk = tid >> 6;    // 0..3
        int th = tid & 63;
        for (int r = 0; r < 16; ++r) {
            int kl = r * 4 + tk;
            tile[kl][th] = __float2bfloat16(src[(size_t)(kl0 + kl) * H_ + h0 + th]);
        }
        __syncthreads();
        for (int r = 0; r < 16; ++r) {
            int hl = r * 4 + tk;           // h within tile
            int h  = h0 + hl;
            int np = (h >> 4) * 80 + g * 16 + (h & 15);
            WT[(size_t)np * K_ + k0 + th] = tile[th][hl];
        }
    }
}

// ---------------------------------------------------------------------------
// Fused GEMM + LSTM epilogue. 512 threads = 8 waves of 32x80 (2x5 frags,
// acc = 40 AGPR/wave) -> ~2x occupancy vs 4-wave/64x80 version. Same block
// tile 128x160, same LDS staging via global_load_lds width 16.
// ---------------------------------------------------------------------------
#define GLD16(gp, lp)                                                              \
    __builtin_amdgcn_global_load_lds(                                              \
        (const __attribute__((address_space(1))) unsigned int*)(gp),               \
        (__attribute__((address_space(3))) unsigned int*)(lp), 16, 0, 0)

__global__ __launch_bounds__(512, 4) void gemm_fused_kernel(
    const __hip_bfloat16* __restrict__ A, const __hip_bfloat16* __restrict__ WT,
    const float* __restrict__ ct, const float* __restrict__ cs,
    const float* __restrict__ bi, const float* __restrict__ bfs,
    const float* __restrict__ bft, const float* __restrict__ bo,
    const float* __restrict__ bc, float* __restrict__ out) {
    __shared__ alignas(16) unsigned short sA[128 * 32];
    __shared__ alignas(16) unsigned short sB[NT_ * 32];

    int tid = threadIdx.x;
    int m0 = blockIdx.x * 128;   // row tile (fast axis -> W col-tile stays L2-hot)
    int n0 = blockIdx.y * NT_;   // W column tile (slow axis)
    int wid  = tid >> 6, lane = tid & 63;
    int wm   = wid >> 1;         // 0..3: 32-row slice
    int wn   = wid & 1;          // 0..1: 80-col (h-group) slice
    int quad = lane >> 4, l15 = lane & 15;

    int h = (blockIdx.y * 2 + wn) * 16 + l15;   // this lane's h column
    float Bi = bi[h], Bfs = bfs[h], Bft = bft[h], Bo = bo[h], Bc = bc[h];

    f32x4 acc[2][5];
#pragma unroll
    for (int i = 0; i < 2; ++i)
#pragma unroll
        for (int j = 0; j < 5; ++j)
            acc[i][j] = (f32x4){0.f, 0.f, 0.f, 0.f};

    // staging: chunk c = tid -> row c>>2, 16B col (c&3)*8; 512 A-chunks, 640 B-chunks
    int srow = tid >> 2;
    int scol = (tid & 3) * 8;
    const __hip_bfloat16* Abase = A  + (size_t)(m0 + srow) * K_ + scol;
    const __hip_bfloat16* Bbase = WT + (size_t)(n0 + srow) * K_ + scol;
    unsigned short* AsDst = sA + tid * 8;   // byte tid*16
    unsigned short* BsDst = sB + tid * 8;

    for (int k0 = 0; k0 < K_; k0 += 32) {
        GLD16(Abase + k0, AsDst);
        GLD16(Bbase + k0, BsDst);
        if (tid < 128)  // B rows 128..159
            GLD16(Bbase + k0 + (size_t)128 * K_, BsDst + 4096);
        __syncthreads();

        short8 a[2], b[5];
#pragma unroll
        for (int i = 0; i < 2; ++i)
            a[i] = *(const short8*)(sA + (wm * 32 + i * 16 + l15) * 32 + quad * 8);
#pragma unroll
        for (int j = 0; j < 5; ++j)
            b[j] = *(const short8*)(sB + (wn * 80 + j * 16 + l15) * 32 + quad * 8);
#pragma unroll
        for (int j = 0; j < 5; ++j)
#pragma unroll
            for (int i = 0; i < 2; ++i)
                acc[i][j] = __builtin_amdgcn_mfma_f32_16x16x32_bf16(a[i], b[j], acc[i][j], 0, 0, 0);
        __syncthreads();
    }

    // Lane-local LSTM epilogue. C/D layout: col = l15 (h), row = quad*4 + r.
#pragma unroll
    for (int i = 0; i < 2; ++i) {
        int row0 = m0 + wm * 32 + i * 16 + quad * 4;
#pragma unroll
        for (int r = 0; r < 4; ++r) {
            size_t idx = (size_t)(row0 + r) * H_ + h;
            float i_n  = sigf(acc[i][0][r] + Bi);
            float fs_n = sigf(acc[i][1][r] + Bfs);
            float ft_n = sigf(acc[i][2][r] + Bft);
            float o_n  = sigf(acc[i][3][r] + Bo);
            float c_n  = tanhfast(acc[i][4][r] + Bc);
            float ch   = i_n * c_n + ft_n * ct[idx] + fs_n * cs[idx];
            out[idx] = o_n * tanhfast(ch);
            out[(size_t)B_ * H_ + idx] = ch;
        }
    }
}

// ---------------------------------------------------------------------------
// Fallback (ws too small): one block per row, fp32 direct. Slow but correct.
// ---------------------------------------------------------------------------
struct AllW {
    const float* U[5];
    const float* Wt[5];
    const float* Ws[5];
    const float* bias[5];
};

__global__ __launch_bounds__(512) void fallback_kernel(const float* __restrict__ x,
                                                       const float* __restrict__ ht,
                                                       const float* __restrict__ hs,
                                                       const float* __restrict__ ct,
                                                       const float* __restrict__ cs,
                                                       AllW w, float* __restrict__ out) {
    __shared__ float arow[K_];
    int b = blockIdx.x;
    int h = threadIdx.x;
    for (int k = h; k < K_; k += 512) {
        float v;
        if (k < D_)           v = x[b * D_ + k];
        else if (k < D_ + H_) v = ht[b * H_ + k - D_];
        else                  v = hs[b * H_ + k - D_ - H_];
        arow[k] = v;
    }
    __syncthreads();
    float g[5];
    for (int gi = 0; gi < 5; ++gi) {
        float s = w.bias[gi][h];
        const float* U = w.U[gi];
        for (int k = 0; k < D_; ++k) s += arow[k] * U[(size_t)k * H_ + h];
        const float* Wt = w.Wt[gi];
        for (int k = 0; k < H_; ++k) s += arow[D_ + k] * Wt[(size_t)k * H_ + h];
        const float* Ws = w.Ws[gi];
        for (int k = 0; k < H_; ++k) s += arow[D_ + H_ + k] * Ws[(size_t)k * H_ + h];
        g[gi] = s;
    }
    int idx = b * H_ + h;
    float i_n = sigf(g[0]), fs_n = sigf(g[1]), ft_n = sigf(g[2]), o_n = sigf(g[3]);
    float c_n = tanhfast(g[4]);
    float ch  = i_n * c_n + ft_n * ct[idx] + fs_n * cs[idx];
    out[idx] = o_n * tanhfast(ch);
    out[(size_t)B_ * H_ + idx] = ch;
}

// ---------------------------------------------------------------------------
extern "C" void kernel_launch(void* const* d_in, const int* in_sizes, int n_in,
                              void* d_out, int out_size, void* d_ws, size_t ws_size,
                              hipStream_t stream) {
    const float* x  = (const float*)d_in[0];
    const float* ht = (const float*)d_in[1];
    const float* hs = (const float*)d_in[2];
    const float* ct = (const float*)d_in[3];
    const float* cs = (const float*)d_in[4];

    WPtrs wp;
    AllW  aw;
    const float* bias[5];
    for (int g = 0; g < 5; ++g) {
        wp.U[g]  = (const float*)d_in[5 + g * 4 + 0];
        wp.Wt[g] = (const float*)d_in[5 + g * 4 + 1];
        wp.Ws[g] = (const float*)d_in[5 + g * 4 + 2];
        bias[g]  = (const float*)d_in[5 + g * 4 + 3];
        aw.U[g] = wp.U[g]; aw.Wt[g] = wp.Wt[g]; aw.Ws[g] = wp.Ws[g]; aw.bias[g] = bias[g];
    }
    float* out = (float*)d_out;

    size_t szA = (size_t)B_ * K_ * 2;  // 20 MB
    size_t szW = (size_t)N_ * K_ * 2;  // 6.25 MB

    if (ws_size >= szA + szW) {
        __hip_bfloat16* Abf = (__hip_bfloat16*)d_ws;
        __hip_bfloat16* WT  = (__hip_bfloat16*)((char*)d_ws + szA);

        prep_kernel<<<5120 + 800, 256, 0, stream>>>(x, ht, hs, wp, Abf, WT);
        gemm_fused_kernel<<<dim3(B_ / 128, N_ / NT_), 512, 0, stream>>>(
            Abf, WT, ct, cs, bias[0], bias[1], bias[2], bias[3], bias[4], out);
    } else {
        fallback_kernel<<<B_, 512, 0, stream>>>(x, ht, hs, ct, cs, aw, out);
    }
}

// Round 7
// 235.555 us; speedup vs baseline: 1.4490x; 1.0298x over previous
//
#include <hip/hip_runtime.h>
#include <hip/hip_bf16.h>
#include <cstdint>
#include <cstddef>

// Problem constants
#define B_  8192
#define D_  256
#define H_  512
#define K_  1280   // D + 2H
#define N_  2560   // 5H
#define NT_ 320    // N-tile: 2 h-groups of (32 h x 5 gates)

typedef short short8  __attribute__((ext_vector_type(8)));
typedef float f32x4   __attribute__((ext_vector_type(4)));
typedef float f32x16  __attribute__((ext_vector_type(16)));

__device__ __forceinline__ float sigf(float x)     { return 1.f / (1.f + __expf(-x)); }
__device__ __forceinline__ float tanhfast(float x) { return 1.f - 2.f / (__expf(2.f * x) + 1.f); }

// ---------------------------------------------------------------------------
// prep: merged convA + convW (one launch).
// Blocks [0, 5120): convA — pack [x | h_t | h_s] -> bf16 A[B_, K_], 8 elem/thr.
// Blocks [5120, 5920): convW — bf16 WT[n',k], n' = (h>>5)*160 + g*32 + (h&31).
// ---------------------------------------------------------------------------
struct WPtrs {
    const float* U[5];
    const float* Wt[5];
    const float* Ws[5];
};

__global__ void prep_kernel(const float* __restrict__ x, const float* __restrict__ ht,
                            const float* __restrict__ hs, WPtrs p,
                            __hip_bfloat16* __restrict__ A, __hip_bfloat16* __restrict__ WT) {
    __shared__ __hip_bfloat16 tile[64][72];  // used by convW part only
    int bid = blockIdx.x;
    if (bid < 5120) {
        // ---- convA ----
        int t = bid * 256 + threadIdx.x;   // over B_*K_/8
        int idx8 = t * 8;
        int b = idx8 / K_;
        int k = idx8 - b * K_;
        const float* src;
        if (k < D_)            src = x  + (size_t)b * D_ + k;
        else if (k < D_ + H_)  src = ht + (size_t)b * H_ + (k - D_);
        else                   src = hs + (size_t)b * H_ + (k - D_ - H_);
        f32x4 v0 = *(const f32x4*)(src);
        f32x4 v1 = *(const f32x4*)(src + 4);
        union { short8 s; __hip_bfloat16 h[8]; } o;
        o.h[0] = __float2bfloat16(v0[0]); o.h[1] = __float2bfloat16(v0[1]);
        o.h[2] = __float2bfloat16(v0[2]); o.h[3] = __float2bfloat16(v0[3]);
        o.h[4] = __float2bfloat16(v1[0]); o.h[5] = __float2bfloat16(v1[1]);
        o.h[6] = __float2bfloat16(v1[2]); o.h[7] = __float2bfloat16(v1[3]);
        *(short8*)(A + idx8) = o.s;
    } else {
        // ---- convW ----  bid2 = hblk + 8*(kblk + 20*g)
        int bid2 = bid - 5120;
        int hblk = bid2 & 7;
        int kblk = (bid2 >> 3) % 20;
        int g    = bid2 / 160;
        int k0 = kblk * 64;
        int h0 = hblk * 64;
        const float* src; int kl0;
        if (k0 < 256)      { src = p.U[g];  kl0 = k0; }
        else if (k0 < 768) { src = p.Wt[g]; kl0 = k0 - 256; }
        else               { src = p.Ws[g]; kl0 = k0 - 768; }
        int tid = threadIdx.x;
        int tk = tid >> 6;    // 0..3
        int th = tid & 63;
        for (int r = 0; r < 16; ++r) {
            int kl = r * 4 + tk;
            tile[kl][th] = __float2bfloat16(src[(size_t)(kl0 + kl) * H_ + h0 + th]);
        }
        __syncthreads();
        for (int r = 0; r < 16; ++r) {
            int hl = r * 4 + tk;           // h within tile
            int h  = h0 + hl;
            int np = (h >> 5) * 160 + g * 32 + (h & 31);
            WT[(size_t)np * K_ + k0 + th] = tile[th][hl];
        }
    }
}

// ---------------------------------------------------------------------------
// Fused GEMM + LSTM epilogue, 32x32x16 MFMA.
// Block tile 128x320 (= 64 h x 5 gates), 4 waves = 2(m) x 2(n); wave tile
// 64x160 = 2 m-frags x 5 n-frags (one gate each), acc = 160 VGPR/lane.
// LDS layout: [row][32 k] with k-chunk (16B) XOR-swizzled by (row>>1)&3 to
// spread frag reads across banks. Staging via global_load_lds width 16.
// ---------------------------------------------------------------------------
#define GLD16(gp, lp)                                                              \
    __builtin_amdgcn_global_load_lds(                                              \
        (const __attribute__((address_space(1))) unsigned int*)(gp),               \
        (__attribute__((address_space(3))) unsigned int*)(lp), 16, 0, 0)

__global__ __launch_bounds__(256, 2) void gemm_fused_kernel(
    const __hip_bfloat16* __restrict__ A, const __hip_bfloat16* __restrict__ WT,
    const float* __restrict__ ct, const float* __restrict__ cs,
    const float* __restrict__ bi, const float* __restrict__ bfs,
    const float* __restrict__ bft, const float* __restrict__ bo,
    const float* __restrict__ bc, float* __restrict__ out) {
    __shared__ alignas(16) unsigned short sA[128 * 32];  //  8 KB
    __shared__ alignas(16) unsigned short sB[NT_ * 32];  // 20 KB

    int tid = threadIdx.x;
    int m0 = blockIdx.x * 128;   // row tile (fast axis -> W col-tile L2-hot per XCD)
    int n0 = blockIdx.y * NT_;   // W column tile (slow axis)
    int wid  = tid >> 6, lane = tid & 63;
    int wm   = wid >> 1;         // 0..1: 64-row slice
    int wn   = wid & 1;          // 0..1: 160-col (32-h-group) slice
    int half = lane >> 5, l31 = lane & 31;

    int hg = blockIdx.y * 2 + wn;      // 32-h group
    int h  = hg * 32 + l31;            // this lane's h column
    float Bi = bi[h], Bfs = bfs[h], Bft = bft[h], Bo = bo[h], Bc = bc[h];

    f32x16 acc[2][5];
#pragma unroll
    for (int i = 0; i < 2; ++i)
#pragma unroll
        for (int j = 0; j < 5; ++j)
            acc[i][j] = (f32x16)(0.f);

    // Staging: chunk c -> LDS bytes [c*16, c*16+16); row = c>>2, chunk pos = c&3.
    // Global k-chunk loaded = pos ^ ((row>>1)&3)  (bank swizzle, bijective per row).
    const __hip_bfloat16* aSrc[2]; unsigned short* aDst[2];
#pragma unroll
    for (int i = 0; i < 2; ++i) {
        int c = tid + 256 * i;
        int row = c >> 2, pos = c & 3;
        int kc = pos ^ ((row >> 1) & 3);
        aSrc[i] = A + (size_t)(m0 + row) * K_ + kc * 8;
        aDst[i] = sA + c * 8;
    }
    const __hip_bfloat16* bSrc[5]; unsigned short* bDst[5];
#pragma unroll
    for (int i = 0; i < 5; ++i) {
        int c = tid + 256 * i;
        int row = c >> 2, pos = c & 3;
        int kc = pos ^ ((row >> 1) & 3);
        bSrc[i] = WT + (size_t)(n0 + row) * K_ + kc * 8;
        bDst[i] = sB + c * 8;
    }

    // Frag read offsets (shorts): row*32 + (chunk ^ ((row>>1)&3))*8, chunk = ks*2+half
    int arow[2], brow[5];
#pragma unroll
    for (int i = 0; i < 2; ++i) arow[i] = wm * 64 + i * 32 + l31;
#pragma unroll
    for (int j = 0; j < 5; ++j) brow[j] = wn * 160 + j * 32 + l31;

    for (int k0 = 0; k0 < K_; k0 += 32) {
#pragma unroll
        for (int i = 0; i < 2; ++i) GLD16(aSrc[i] + k0, aDst[i]);
#pragma unroll
        for (int i = 0; i < 5; ++i) GLD16(bSrc[i] + k0, bDst[i]);
        __syncthreads();

#pragma unroll
        for (int ks = 0; ks < 2; ++ks) {
            short8 a[2], b[5];
#pragma unroll
            for (int i = 0; i < 2; ++i) {
                int pos = (ks * 2 + half) ^ ((arow[i] >> 1) & 3);
                a[i] = *(const short8*)(sA + arow[i] * 32 + pos * 8);
            }
#pragma unroll
            for (int j = 0; j < 5; ++j) {
                int pos = (ks * 2 + half) ^ ((brow[j] >> 1) & 3);
                b[j] = *(const short8*)(sB + brow[j] * 32 + pos * 8);
            }
#pragma unroll
            for (int j = 0; j < 5; ++j)
#pragma unroll
                for (int i = 0; i < 2; ++i)
                    acc[i][j] = __builtin_amdgcn_mfma_f32_32x32x16_bf16(a[i], b[j], acc[i][j], 0, 0, 0);
        }
        __syncthreads();
    }

    // Lane-local LSTM epilogue.
    // 32x32 C/D layout: col = lane&31 (h), row = (r&3) + 8*(r>>2) + 4*half.
#pragma unroll
    for (int i = 0; i < 2; ++i) {
        int rbase = m0 + wm * 64 + i * 32 + 4 * half;
#pragma unroll
        for (int r = 0; r < 16; ++r) {
            int row = rbase + (r & 3) + 8 * (r >> 2);
            size_t idx = (size_t)row * H_ + h;
            float i_n  = sigf(acc[i][0][r] + Bi);
            float fs_n = sigf(acc[i][1][r] + Bfs);
            float ft_n = sigf(acc[i][2][r] + Bft);
            float o_n  = sigf(acc[i][3][r] + Bo);
            float c_n  = tanhfast(acc[i][4][r] + Bc);
            float ch   = i_n * c_n + ft_n * ct[idx] + fs_n * cs[idx];
            out[idx] = o_n * tanhfast(ch);
            out[(size_t)B_ * H_ + idx] = ch;
        }
    }
}

// ---------------------------------------------------------------------------
// Fallback (ws too small): one block per row, fp32 direct. Slow but correct.
// ---------------------------------------------------------------------------
struct AllW {
    const float* U[5];
    const float* Wt[5];
    const float* Ws[5];
    const float* bias[5];
};

__global__ __launch_bounds__(512) void fallback_kernel(const float* __restrict__ x,
                                                       const float* __restrict__ ht,
                                                       const float* __restrict__ hs,
                                                       const float* __restrict__ ct,
                                                       const float* __restrict__ cs,
                                                       AllW w, float* __restrict__ out) {
    __shared__ float arow[K_];
    int b = blockIdx.x;
    int h = threadIdx.x;
    for (int k = h; k < K_; k += 512) {
        float v;
        if (k < D_)           v = x[b * D_ + k];
        else if (k < D_ + H_) v = ht[b * H_ + k - D_];
        else                  v = hs[b * H_ + k - D_ - H_];
        arow[k] = v;
    }
    __syncthreads();
    float g[5];
    for (int gi = 0; gi < 5; ++gi) {
        float s = w.bias[gi][h];
        const float* U = w.U[gi];
        for (int k = 0; k < D_; ++k) s += arow[k] * U[(size_t)k * H_ + h];
        const float* Wt = w.Wt[gi];
        for (int k = 0; k < H_; ++k) s += arow[D_ + k] * Wt[(size_t)k * H_ + h];
        const float* Ws = w.Ws[gi];
        for (int k = 0; k < H_; ++k) s += arow[D_ + H_ + k] * Ws[(size_t)k * H_ + h];
        g[gi] = s;
    }
    int idx = b * H_ + h;
    float i_n = sigf(g[0]), fs_n = sigf(g[1]), ft_n = sigf(g[2]), o_n = sigf(g[3]);
    float c_n = tanhfast(g[4]);
    float ch  = i_n * c_n + ft_n * ct[idx] + fs_n * cs[idx];
    out[idx] = o_n * tanhfast(ch);
    out[(size_t)B_ * H_ + idx] = ch;
}

// ---------------------------------------------------------------------------
extern "C" void kernel_launch(void* const* d_in, const int* in_sizes, int n_in,
                              void* d_out, int out_size, void* d_ws, size_t ws_size,
                              hipStream_t stream) {
    const float* x  = (const float*)d_in[0];
    const float* ht = (const float*)d_in[1];
    const float* hs = (const float*)d_in[2];
    const float* ct = (const float*)d_in[3];
    const float* cs = (const float*)d_in[4];

    WPtrs wp;
    AllW  aw;
    const float* bias[5];
    for (int g = 0; g < 5; ++g) {
        wp.U[g]  = (const float*)d_in[5 + g * 4 + 0];
        wp.Wt[g] = (const float*)d_in[5 + g * 4 + 1];
        wp.Ws[g] = (const float*)d_in[5 + g * 4 + 2];
        bias[g]  = (const float*)d_in[5 + g * 4 + 3];
        aw.U[g] = wp.U[g]; aw.Wt[g] = wp.Wt[g]; aw.Ws[g] = wp.Ws[g]; aw.bias[g] = bias[g];
    }
    float* out = (float*)d_out;

    size_t szA = (size_t)B_ * K_ * 2;  // 20 MB
    size_t szW = (size_t)N_ * K_ * 2;  // 6.25 MB

    if (ws_size >= szA + szW) {
        __hip_bfloat16* Abf = (__hip_bfloat16*)d_ws;
        __hip_bfloat16* WT  = (__hip_bfloat16*)((char*)d_ws + szA);

        prep_kernel<<<5120 + 800, 256, 0, stream>>>(x, ht, hs, wp, Abf, WT);
        gemm_fused_kernel<<<dim3(B_ / 128, N_ / NT_), 256, 0, stream>>>(
            Abf, WT, ct, cs, bias[0], bias[1], bias[2], bias[3], bias[4], out);
    } else {
        fallback_kernel<<<B_, 512, 0, stream>>>(x, ht, hs, ct, cs, aw, out);
    }
}